// Round 1
// baseline (516.584 us; speedup 1.0000x reference)
//
#include <hip/hip_runtime.h>

#define B_  4
#define C_  64
#define N_  4096
#define QT  64
#define KT  64
#define NKT (N_/KT)

// ---------------------------------------------------------------------------
// Kernel 1: QKV projection (three 1x1 convs).
//   q[b,o,n] = sum_c W1[o,c] x[b,c,n] + b1[o]   -> qc (B,C,N)
//   k[b,o,n] = ... W2 ... + b2[o]               -> kc (B,C,N)
//   vT[b,n,o] = ... W3 ... + b3[o]              -> vT (B,N,C)  (transposed for PV)
// Block: 256 thr = 4 waves; wave w handles output channels [16w,16w+16) for a
// 64-pixel tile. W rows read via wave-uniform addresses -> scalar loads.
// ---------------------------------------------------------------------------
__global__ __launch_bounds__(256) void qkv_proj(
    const float* __restrict__ x,
    const float* __restrict__ W1, const float* __restrict__ b1,
    const float* __restrict__ W2, const float* __restrict__ b2,
    const float* __restrict__ W3, const float* __restrict__ b3,
    float* __restrict__ qc, float* __restrict__ kc, float* __restrict__ vT)
{
    const int tid = threadIdx.x;
    const int tn  = tid & 63;                                   // pixel in tile
    const int to  = __builtin_amdgcn_readfirstlane(tid >> 6);   // wave id 0..3
    const int b   = blockIdx.y;
    const int n   = blockIdx.x * 64 + tn;

    const float* xb = x + (size_t)b * C_ * N_;

    float xv[64];
    #pragma unroll
    for (int c = 0; c < 64; ++c) xv[c] = xb[c * N_ + n];        // coalesced

    float vacc[16];
    #pragma unroll
    for (int og = 0; og < 16; ++og) {
        const int o = to * 16 + og;                             // wave-uniform
        const float4* w1r = (const float4*)(W1 + o * 64);
        const float4* w2r = (const float4*)(W2 + o * 64);
        const float4* w3r = (const float4*)(W3 + o * 64);
        float aq = b1[o], ak = b2[o], av = b3[o];
        #pragma unroll
        for (int c4 = 0; c4 < 16; ++c4) {
            float4 w1v = w1r[c4], w2v = w2r[c4], w3v = w3r[c4];
            const float x0 = xv[4*c4+0], x1 = xv[4*c4+1], x2 = xv[4*c4+2], x3 = xv[4*c4+3];
            aq = fmaf(w1v.x, x0, aq); aq = fmaf(w1v.y, x1, aq);
            aq = fmaf(w1v.z, x2, aq); aq = fmaf(w1v.w, x3, aq);
            ak = fmaf(w2v.x, x0, ak); ak = fmaf(w2v.y, x1, ak);
            ak = fmaf(w2v.z, x2, ak); ak = fmaf(w2v.w, x3, ak);
            av = fmaf(w3v.x, x0, av); av = fmaf(w3v.y, x1, av);
            av = fmaf(w3v.z, x2, av); av = fmaf(w3v.w, x3, av);
        }
        qc[((size_t)b * C_ + o) * N_ + n] = aq;                 // coalesced over n
        kc[((size_t)b * C_ + o) * N_ + n] = ak;
        vacc[og] = av;
    }
    float4* vout = (float4*)(vT + ((size_t)b * N_ + n) * C_ + to * 16);
    vout[0] = make_float4(vacc[0],  vacc[1],  vacc[2],  vacc[3]);
    vout[1] = make_float4(vacc[4],  vacc[5],  vacc[6],  vacc[7]);
    vout[2] = make_float4(vacc[8],  vacc[9],  vacc[10], vacc[11]);
    vout[3] = make_float4(vacc[12], vacc[13], vacc[14], vacc[15]);
}

// ---------------------------------------------------------------------------
// Kernel 2: fp32 flash attention + residual epilogue.
// Block: 256 thr (16x16), 64 queries, key tiles of 64, double-buffered K/V.
// Thread (ty,tx): S/P micro-tile rows qi=4ty+a, cols mj=4tx+b;
//                 O micro-tile rows qi=4ty+a, channels c=4tx+b.
// ---------------------------------------------------------------------------
__device__ __forceinline__ void fma16(const float4& av, const float4& bv, float acc[4][4])
{
    const float aa[4] = {av.x, av.y, av.z, av.w};
    const float bb[4] = {bv.x, bv.y, bv.z, bv.w};
    #pragma unroll
    for (int i = 0; i < 4; ++i)
        #pragma unroll
        for (int j = 0; j < 4; ++j)
            acc[i][j] = fmaf(aa[i], bb[j], acc[i][j]);
}

__global__ __launch_bounds__(256) void flash_attn(
    const float* __restrict__ qc, const float* __restrict__ kc,
    const float* __restrict__ vT, const float* __restrict__ x,
    const float* __restrict__ alpha_p, float* __restrict__ out)
{
    __shared__ float Qs[64][64];        // [d][i]
    __shared__ float Ks[2][64][64];     // [d][j]
    __shared__ float Vs[2][64][64];     // [m][c]
    __shared__ float Ps[64][68];        // [m][i], pad->16B-aligned rows, low conflict

    const int tid = threadIdx.x;
    const int tx  = tid & 15;
    const int ty  = tid >> 4;
    const int tx4 = tx * 4;
    const int ty4 = ty * 4;
    const int b   = blockIdx.y;
    const int q0  = blockIdx.x * QT;

    const float* qb = qc + (size_t)b * C_ * N_;
    const float* kb = kc + (size_t)b * C_ * N_;
    const float* vb = vT + (size_t)b * N_ * C_;

    const int sr = tid >> 4;            // staging row base (+16*it)

    // Stage Q and tile 0 of K/V.
    #pragma unroll
    for (int it = 0; it < 4; ++it) {
        const int r = sr + 16 * it;
        *(float4*)&Qs[r][tx4]    = *(const float4*)(qb + r * N_ + q0 + tx4);
        *(float4*)&Ks[0][r][tx4] = *(const float4*)(kb + r * N_ + tx4);
        *(float4*)&Vs[0][r][tx4] = *(const float4*)(vb + r * C_ + tx4);
    }
    __syncthreads();

    float m_r[4], l_r[4], o_r[4][4];
    #pragma unroll
    for (int a = 0; a < 4; ++a) {
        m_r[a] = -1e30f; l_r[a] = 0.f;
        #pragma unroll
        for (int j = 0; j < 4; ++j) o_r[a][j] = 0.f;
    }

    int cur = 0;
    float4 kpre[4], vpre[4];

    for (int t = 0; t < NKT; ++t) {
        const bool pf = (t + 1 < NKT);
        if (pf) {                        // prefetch next tile into regs (VMEM in flight over S-phase)
            #pragma unroll
            for (int it = 0; it < 4; ++it) {
                const int r = sr + 16 * it;
                kpre[it] = *(const float4*)(kb + r * N_ + (t + 1) * KT + tx4);
                vpre[it] = *(const float4*)(vb + ((t + 1) * KT + r) * C_ + tx4);
            }
        }

        // ---- S = Q . K^T (outer product over d) ----
        float s[4][4] = {};
        #pragma unroll 8
        for (int d = 0; d < 64; ++d) {
            const float4 qv = *(const float4*)&Qs[d][ty4];
            const float4 kv = *(const float4*)&Ks[cur][d][tx4];
            fma16(qv, kv, s);
        }

        // ---- online softmax over the 64-key tile ----
        float p[4][4];
        #pragma unroll
        for (int a = 0; a < 4; ++a) {
            float rm = fmaxf(fmaxf(s[a][0], s[a][1]), fmaxf(s[a][2], s[a][3]));
            rm = fmaxf(rm, __shfl_xor(rm, 1));
            rm = fmaxf(rm, __shfl_xor(rm, 2));
            rm = fmaxf(rm, __shfl_xor(rm, 4));
            rm = fmaxf(rm, __shfl_xor(rm, 8));
            const float nm   = fmaxf(m_r[a], rm);
            const float corr = __expf(m_r[a] - nm);
            m_r[a] = nm;
            float rs = 0.f;
            #pragma unroll
            for (int j = 0; j < 4; ++j) { p[a][j] = __expf(s[a][j] - nm); rs += p[a][j]; }
            rs += __shfl_xor(rs, 1);
            rs += __shfl_xor(rs, 2);
            rs += __shfl_xor(rs, 4);
            rs += __shfl_xor(rs, 8);
            l_r[a] = l_r[a] * corr + rs;
            #pragma unroll
            for (int j = 0; j < 4; ++j) o_r[a][j] *= corr;
        }

        // ---- write P^T to LDS; land staged K/V into the other buffer ----
        #pragma unroll
        for (int j = 0; j < 4; ++j)
            *(float4*)&Ps[tx4 + j][ty4] = make_float4(p[0][j], p[1][j], p[2][j], p[3][j]);
        if (pf) {
            const int nb = cur ^ 1;
            #pragma unroll
            for (int it = 0; it < 4; ++it) {
                const int r = sr + 16 * it;
                *(float4*)&Ks[nb][r][tx4] = kpre[it];
                *(float4*)&Vs[nb][r][tx4] = vpre[it];
            }
        }
        __syncthreads();

        // ---- O += P . V^T (outer product over m) ----
        #pragma unroll 8
        for (int mm = 0; mm < 64; ++mm) {
            const float4 pv = *(const float4*)&Ps[mm][ty4];
            const float4 vv = *(const float4*)&Vs[cur][mm][tx4];
            fma16(pv, vv, o_r);
        }
        __syncthreads();
        cur ^= 1;
    }

    // ---- epilogue: normalize, transpose via LDS, out = x + alpha*E ----
    const float alpha = alpha_p[0];
    float* Olds = &Ks[0][0][0];                       // reuse; stride 65 (conflict-free)
    #pragma unroll
    for (int a = 0; a < 4; ++a) {
        const float inv_l = 1.f / l_r[a];
        #pragma unroll
        for (int j = 0; j < 4; ++j)
            Olds[(ty4 + a) * 65 + tx4 + j] = o_r[a][j] * inv_l;
    }
    __syncthreads();

    const float* xb = x   + (size_t)b * C_ * N_;
    float*       ob = out + (size_t)b * C_ * N_;
    const int i  = tid & 63;
    const int c0 = tid >> 6;
    #pragma unroll
    for (int rep = 0; rep < 16; ++rep) {
        const int c = rep * 4 + c0;
        const float e = Olds[i * 65 + c];
        ob[c * N_ + q0 + i] = xb[c * N_ + q0 + i] + alpha * e;   // coalesced
    }
}

// ---------------------------------------------------------------------------
extern "C" void kernel_launch(void* const* d_in, const int* in_sizes, int n_in,
                              void* d_out, int out_size, void* d_ws, size_t ws_size,
                              hipStream_t stream)
{
    const float* x     = (const float*)d_in[0];
    const float* W1    = (const float*)d_in[1];
    const float* b1    = (const float*)d_in[2];
    const float* W2    = (const float*)d_in[3];
    const float* b2    = (const float*)d_in[4];
    const float* W3    = (const float*)d_in[5];
    const float* b3    = (const float*)d_in[6];
    const float* alpha = (const float*)d_in[7];
    float* out = (float*)d_out;

    float* qc = (float*)d_ws;                       // (B,C,N) 4 MB
    float* kc = qc + (size_t)B_ * C_ * N_;          // (B,C,N) 4 MB
    float* vT = kc + (size_t)B_ * C_ * N_;          // (B,N,C) 4 MB

    qkv_proj<<<dim3(N_ / 64, B_), 256, 0, stream>>>(x, W1, b1, W2, b2, W3, b3, qc, kc, vT);
    flash_attn<<<dim3(N_ / QT, B_), 256, 0, stream>>>(qc, kc, vT, x, alpha, out);
}

// Round 2
// 391.635 us; speedup vs baseline: 1.3190x; 1.3190x over previous
//
#include <hip/hip_runtime.h>

typedef __attribute__((ext_vector_type(8))) short          short8;   // 8 bf16 = one MFMA A/B fragment
typedef __attribute__((ext_vector_type(4))) float          f32x4;
typedef __attribute__((ext_vector_type(8))) unsigned short ushort8;

#define B_    4
#define C_    64
#define N_    4096
#define QT    64            // queries per block
#define KT    256           // keys per tile
#define NT    (N_/KT)       // 16
#define WKEY  32            // keys per wave per tile

// ---------------- bf16 helpers (RTN) ----------------
__device__ __forceinline__ unsigned short f2bf(float f) {
    unsigned u = __builtin_bit_cast(unsigned, f);
    return (unsigned short)((u + 0x7FFFu + ((u >> 16) & 1u)) >> 16);
}
__device__ __forceinline__ float bf2f(unsigned short h) {
    return __builtin_bit_cast(float, (unsigned)h << 16);
}

// ---------------- DPP 16-lane reductions (VALU pipe, no LDS) ----------------
template<int ROR>
__device__ __forceinline__ float ror16(float v) {
    return __builtin_bit_cast(float,
        __builtin_amdgcn_update_dpp(__builtin_bit_cast(int, v), __builtin_bit_cast(int, v),
                                    0x120 + ROR, 0xF, 0xF, true));
}
__device__ __forceinline__ float rmax16(float v) {
    v = fmaxf(v, ror16<1>(v)); v = fmaxf(v, ror16<2>(v));
    v = fmaxf(v, ror16<4>(v)); v = fmaxf(v, ror16<8>(v));
    return v;
}
__device__ __forceinline__ float rsum16(float v) {
    v += ror16<1>(v); v += ror16<2>(v); v += ror16<4>(v); v += ror16<8>(v);
    return v;
}

__device__ __forceinline__ f32x4 mfma16(short8 a, short8 b, f32x4 c) {
    return __builtin_amdgcn_mfma_f32_16x16x32_bf16(a, b, c, 0, 0, 0);
}

// ---------------------------------------------------------------------------
// Kernel 1: QKV projection (fp32 math, bf16 hi/lo outputs).
//   qhi/qlo, khi/klo : (B, N, C) bf16  (pixel-major rows -> MFMA B/A frags contiguous)
//   vhi              : (B, C, N) bf16  (channel-major -> LDS staging rows contiguous)
// ---------------------------------------------------------------------------
__global__ __launch_bounds__(256) void qkv_proj(
    const float* __restrict__ x,
    const float* __restrict__ W1, const float* __restrict__ b1,
    const float* __restrict__ W2, const float* __restrict__ b2,
    const float* __restrict__ W3, const float* __restrict__ b3,
    unsigned short* __restrict__ qhi, unsigned short* __restrict__ qlo,
    unsigned short* __restrict__ khi, unsigned short* __restrict__ klo,
    unsigned short* __restrict__ vhi)
{
    const int tid = threadIdx.x;
    const int tn  = tid & 63;
    const int to  = __builtin_amdgcn_readfirstlane(tid >> 6);   // wave id 0..3
    const int b   = blockIdx.y;
    const int n   = blockIdx.x * 64 + tn;

    const float* xb = x + (size_t)b * C_ * N_;

    float xv[64];
    #pragma unroll
    for (int c = 0; c < 64; ++c) xv[c] = xb[c * N_ + n];        // coalesced

    ushort8 qh8[2], ql8[2], kh8[2], kl8[2];

    #pragma unroll
    for (int og = 0; og < 16; ++og) {
        const int o = to * 16 + og;                             // wave-uniform
        const float4* w1r = (const float4*)(W1 + o * 64);
        const float4* w2r = (const float4*)(W2 + o * 64);
        const float4* w3r = (const float4*)(W3 + o * 64);
        float aq = b1[o], ak = b2[o], av = b3[o];
        #pragma unroll
        for (int c4 = 0; c4 < 16; ++c4) {
            float4 w1v = w1r[c4], w2v = w2r[c4], w3v = w3r[c4];
            const float x0 = xv[4*c4+0], x1 = xv[4*c4+1], x2 = xv[4*c4+2], x3 = xv[4*c4+3];
            aq = fmaf(w1v.x, x0, aq); aq = fmaf(w1v.y, x1, aq);
            aq = fmaf(w1v.z, x2, aq); aq = fmaf(w1v.w, x3, aq);
            ak = fmaf(w2v.x, x0, ak); ak = fmaf(w2v.y, x1, ak);
            ak = fmaf(w2v.z, x2, ak); ak = fmaf(w2v.w, x3, ak);
            av = fmaf(w3v.x, x0, av); av = fmaf(w3v.y, x1, av);
            av = fmaf(w3v.z, x2, av); av = fmaf(w3v.w, x3, av);
        }
        const int s = og >> 3, e = og & 7;
        unsigned short h;
        h = f2bf(aq); qh8[s][e] = h; ql8[s][e] = f2bf(aq - bf2f(h));
        h = f2bf(ak); kh8[s][e] = h; kl8[s][e] = f2bf(ak - bf2f(h));
        vhi[((size_t)b * 64 + o) * N_ + n] = f2bf(av);          // coalesced over n
    }

    const size_t row = ((size_t)b * N_ + n) * 64 + to * 16;
    *(ushort8*)(qhi + row) = qh8[0];  *(ushort8*)(qhi + row + 8) = qh8[1];
    *(ushort8*)(qlo + row) = ql8[0];  *(ushort8*)(qlo + row + 8) = ql8[1];
    *(ushort8*)(khi + row) = kh8[0];  *(ushort8*)(khi + row + 8) = kh8[1];
    *(ushort8*)(klo + row) = kl8[0];  *(ushort8*)(klo + row + 8) = kl8[1];
}

// ---------------------------------------------------------------------------
// Kernel 2: split-bf16 MFMA flash attention + residual epilogue.
// 8 waves x 512 thr; wave w: all 64 queries x keys [t*256 + 32w, +32).
// QK^T: 3-split MFMA (qh*kh + qh*kl + ql*kh), K frags direct from global (L2).
// PV:   P(bf16) x V(bf16-hi) MFMA, V staged in swizzled LDS (double-buffered).
// Online softmax in MFMA C-layout, DPP row reductions, defer-max THR=8.
// End: 8-way partial merge (m,l,O) through LDS + coalesced epilogue.
// ---------------------------------------------------------------------------
__global__ __launch_bounds__(512, 2) void flash_attn(
    const unsigned short* __restrict__ qhi, const unsigned short* __restrict__ qlo,
    const unsigned short* __restrict__ khi, const unsigned short* __restrict__ klo,
    const unsigned short* __restrict__ vhi,
    const float* __restrict__ x, const float* __restrict__ alpha_p,
    float* __restrict__ out)
{
    __shared__ __align__(16) char smA[65536];   // Vs[2][64][512B]  U  Part[8][32][64] f32
    __shared__ __align__(16) char smB[32768];   // Plds[8][4096B]   U  OT[64][65] f32
    __shared__ __align__(16) float Ml[8][2][32];

    const int tid = threadIdx.x;
    const int l   = tid & 63;
    const int w   = tid >> 6;           // wave 0..7
    const int g   = l >> 4;             // k-group 0..3
    const int li  = l & 15;

    // XCD-aware remap: batch b -> XCD pair {2b, 2b+1} (bid%8 round-robin heuristic)
    const int bid = blockIdx.x;
    const int b   = (bid & 7) >> 1;
    const int qtb = ((bid >> 3) << 1) | (bid & 1);
    const int q0  = qtb * QT;

    const unsigned short* qhb = qhi + (size_t)b * N_ * C_;
    const unsigned short* qlb = qlo + (size_t)b * N_ * C_;
    const unsigned short* khb = khi + (size_t)b * N_ * C_;
    const unsigned short* klb = klo + (size_t)b * N_ * C_;
    const unsigned short* vhb = vhi + (size_t)b * C_ * N_;

    // ---- Q hi fragments: persistent in registers ----
    short8 qh[4][2];
    #pragma unroll
    for (int qt = 0; qt < 4; ++qt)
        #pragma unroll
        for (int ks = 0; ks < 2; ++ks)
            qh[qt][ks] = *(const short8*)(const void*)(qhb + ((q0 + qt*16 + li) * 64 + ks*32 + g*8));

    f32x4 o[4][4];
    float m[4][4], lsum[4][4];
    #pragma unroll
    for (int qt = 0; qt < 4; ++qt)
        #pragma unroll
        for (int j = 0; j < 4; ++j) {
            o[qt][j] = (f32x4){0.f, 0.f, 0.f, 0.f};
            m[qt][j] = -1e30f; lsum[qt][j] = 0.f;
        }

    // ---- stage V tile 0 ----
    {
        #pragma unroll
        for (int ch = 0; ch < 4; ++ch) {
            const int pos = ch * 8192 + tid * 16;
            const int c = pos >> 9, cb = pos & 511;
            ushort8 v = *(const ushort8*)(const void*)((const char*)vhb + (size_t)c * (N_*2) + cb);
            const int st = ((cb >> 4) ^ (c & 15));
            *(ushort8*)(void*)(smA + c * 512 + (st << 4)) = v;
        }
    }
    __syncthreads();

    int cur = 0;
    for (int t = 0; t < NT; ++t) {
        const int kb0 = t * KT + w * WKEY;

        // prefetch next V tile into regs (VMEM in flight over compute)
        ushort8 vst[4];
        if (t + 1 < NT) {
            #pragma unroll
            for (int ch = 0; ch < 4; ++ch) {
                const int pos = ch * 8192 + tid * 16;
                const int c = pos >> 9, cb = pos & 511;
                vst[ch] = *(const ushort8*)(const void*)((const char*)vhb + (size_t)c * (N_*2) + (t+1) * 512 + cb);
            }
        }

        // ---- K fragments direct from global (L2-resident), q-lo reload ----
        short8 kh[2][2], kl[2][2], ql[4][2];
        #pragma unroll
        for (int j = 0; j < 2; ++j)
            #pragma unroll
            for (int ks = 0; ks < 2; ++ks) {
                const int off = (kb0 + j*16 + li) * 64 + ks*32 + g*8;
                kh[j][ks] = *(const short8*)(const void*)(khb + off);
                kl[j][ks] = *(const short8*)(const void*)(klb + off);
            }
        #pragma unroll
        for (int qt = 0; qt < 4; ++qt)
            #pragma unroll
            for (int ks = 0; ks < 2; ++ks)
                ql[qt][ks] = *(const short8*)(const void*)(qlb + ((q0 + qt*16 + li) * 64 + ks*32 + g*8));

        // ---- S = Q.K^T, 3-split ----
        f32x4 s[4][2];
        #pragma unroll
        for (int qt = 0; qt < 4; ++qt)
            #pragma unroll
            for (int j = 0; j < 2; ++j) {
                f32x4 acc = (f32x4){0.f, 0.f, 0.f, 0.f};
                acc = mfma16(qh[qt][0], kh[j][0], acc);
                acc = mfma16(qh[qt][1], kh[j][1], acc);
                acc = mfma16(qh[qt][0], kl[j][0], acc);
                acc = mfma16(qh[qt][1], kl[j][1], acc);
                acc = mfma16(ql[qt][0], kh[j][0], acc);
                acc = mfma16(ql[qt][1], kh[j][1], acc);
                s[qt][j] = acc;
            }

        // ---- online softmax (rows = D-layout: q = qt*16 + g*4 + reg) ----
        float rm[4][4];
        bool need = false;
        #pragma unroll
        for (int qt = 0; qt < 4; ++qt)
            #pragma unroll
            for (int r = 0; r < 4; ++r) {
                const float mx = rmax16(fmaxf(s[qt][0][r], s[qt][1][r]));
                rm[qt][r] = mx;
                need |= (mx > m[qt][r] + 8.0f);
            }

        float p0a[4][4], p1a[4][4];
        if (__any(need)) {
            float corr[4][4];
            #pragma unroll
            for (int qt = 0; qt < 4; ++qt)
                #pragma unroll
                for (int r = 0; r < 4; ++r) {
                    const float mn = fmaxf(m[qt][r], rm[qt][r]);
                    corr[qt][r] = __expf(m[qt][r] - mn);
                    m[qt][r] = mn;
                }
            #pragma unroll
            for (int qt = 0; qt < 4; ++qt)
                #pragma unroll
                for (int r = 0; r < 4; ++r) {
                    const float p0 = __expf(s[qt][0][r] - m[qt][r]);
                    const float p1 = __expf(s[qt][1][r] - m[qt][r]);
                    p0a[qt][r] = p0; p1a[qt][r] = p1;
                    lsum[qt][r] = lsum[qt][r] * corr[qt][r] + rsum16(p0 + p1);
                }
            #pragma unroll
            for (int qt = 0; qt < 4; ++qt)
                #pragma unroll
                for (int ct = 0; ct < 4; ++ct)
                    #pragma unroll
                    for (int r = 0; r < 4; ++r)
                        o[qt][ct][r] *= corr[qt][r];
        } else {            // defer-max: no rescale, P bounded by e^8
            #pragma unroll
            for (int qt = 0; qt < 4; ++qt)
                #pragma unroll
                for (int r = 0; r < 4; ++r) {
                    const float p0 = __expf(s[qt][0][r] - m[qt][r]);
                    const float p1 = __expf(s[qt][1][r] - m[qt][r]);
                    p0a[qt][r] = p0; p1a[qt][r] = p1;
                    lsum[qt][r] += rsum16(p0 + p1);
                }
        }

        // ---- write P^ (bf16) to wave-private swizzled LDS ----
        char* Pw = smB + w * 4096;
        #pragma unroll
        for (int qt = 0; qt < 4; ++qt)
            #pragma unroll
            for (int r = 0; r < 4; ++r) {
                const int q = qt*16 + g*4 + r;
                const int k0 = li, k1 = 16 + li;
                *(unsigned short*)(void*)(Pw + q*64 + (((k0>>3) ^ (q&3)) << 4) + (k0&7)*2) = f2bf(p0a[qt][r]);
                *(unsigned short*)(void*)(Pw + q*64 + (((k1>>3) ^ (q&3)) << 4) + (k1&7)*2) = f2bf(p1a[qt][r]);
            }

        // ---- O += P . V ----
        short8 pf[4];
        #pragma unroll
        for (int qt = 0; qt < 4; ++qt) {
            const int q = qt*16 + li;
            pf[qt] = *(const short8*)(const void*)(Pw + q*64 + ((g ^ (q&3)) << 4));
        }
        const char* Vr = smA + cur * 32768;
        #pragma unroll
        for (int ct = 0; ct < 4; ++ct) {
            const int c  = ct*16 + li;
            const int st = ((w*4 + g) ^ (c & 15));
            const short8 vf = *(const short8*)(const void*)(Vr + c*512 + (st << 4));
            #pragma unroll
            for (int qt = 0; qt < 4; ++qt)
                o[qt][ct] = mfma16(pf[qt], vf, o[qt][ct]);
        }

        // ---- land staged V into the other buffer; flip ----
        if (t + 1 < NT) {
            char* Vw = smA + (cur ^ 1) * 32768;
            #pragma unroll
            for (int ch = 0; ch < 4; ++ch) {
                const int pos = ch * 8192 + tid * 16;
                const int c = pos >> 9, cb = pos & 511;
                const int st = ((cb >> 4) ^ (c & 15));
                *(ushort8*)(void*)(Vw + c*512 + (st << 4)) = vst[ch];
            }
        }
        __syncthreads();
        cur ^= 1;
    }

    // ---- 8-way merge of per-wave partials (two 32-row rounds) ----
    float* Part = (float*)smA;
    float* OT   = (float*)smB;
    const float alpha = alpha_p[0];

    #pragma unroll
    for (int r = 0; r < 2; ++r) {
        #pragma unroll
        for (int qh2 = 0; qh2 < 2; ++qh2) {
            const int qt = 2*r + qh2;
            #pragma unroll
            for (int ct = 0; ct < 4; ++ct)
                #pragma unroll
                for (int rg = 0; rg < 4; ++rg)
                    Part[(w*32 + qh2*16 + g*4 + rg) * 64 + ct*16 + li] = o[qt][ct][rg];
            if (li == 0) {
                #pragma unroll
                for (int rg = 0; rg < 4; ++rg) {
                    Ml[w][0][qh2*16 + g*4 + rg] = m[qt][rg];
                    Ml[w][1][qh2*16 + g*4 + rg] = lsum[qt][rg];
                }
            }
        }
        __syncthreads();
        #pragma unroll
        for (int j = 0; j < 4; ++j) {
            const int qlr = 4*w + j;
            float M = -1e30f;
            #pragma unroll
            for (int w2 = 0; w2 < 8; ++w2) M = fmaxf(M, Ml[w2][0][qlr]);
            float L = 0.f, acc = 0.f;
            #pragma unroll
            for (int w2 = 0; w2 < 8; ++w2) {
                const float e = __expf(Ml[w2][0][qlr] - M);
                L   += e * Ml[w2][1][qlr];
                acc += e * Part[(w2*32 + qlr) * 64 + l];
            }
            OT[(32*r + qlr) * 65 + l] = acc / L;
        }
        __syncthreads();
    }

    // ---- epilogue: out = x + alpha * E (coalesced over q) ----
    const int q  = tid & 63;
    const int c0 = tid >> 6;
    #pragma unroll
    for (int rep = 0; rep < 8; ++rep) {
        const int c = rep*8 + c0;
        const size_t idx = ((size_t)b*64 + c) * N_ + q0 + q;
        out[idx] = x[idx] + alpha * OT[q*65 + c];
    }
}

// ---------------------------------------------------------------------------
extern "C" void kernel_launch(void* const* d_in, const int* in_sizes, int n_in,
                              void* d_out, int out_size, void* d_ws, size_t ws_size,
                              hipStream_t stream)
{
    const float* x     = (const float*)d_in[0];
    const float* W1    = (const float*)d_in[1];
    const float* b1    = (const float*)d_in[2];
    const float* W2    = (const float*)d_in[3];
    const float* b2    = (const float*)d_in[4];
    const float* W3    = (const float*)d_in[5];
    const float* b3    = (const float*)d_in[6];
    const float* alpha = (const float*)d_in[7];
    float* out = (float*)d_out;

    const size_t TEN = (size_t)B_ * N_ * C_;        // 1,048,576 elems per tensor
    unsigned short* qhi = (unsigned short*)d_ws;
    unsigned short* qlo = qhi + TEN;
    unsigned short* khi = qlo + TEN;
    unsigned short* klo = khi + TEN;
    unsigned short* vhi = klo + TEN;                // total 10 MiB of ws

    qkv_proj<<<dim3(N_ / 64, B_), 256, 0, stream>>>(x, W1, b1, W2, b2, W3, b3,
                                                    qhi, qlo, khi, klo, vhi);
    flash_attn<<<256, 512, 0, stream>>>(qhi, qlo, khi, klo, vhi, x, alpha, out);
}

// Round 3
// 160.419 us; speedup vs baseline: 3.2202x; 2.4413x over previous
//
#include <hip/hip_runtime.h>

typedef __attribute__((ext_vector_type(8)))  short          short8;
typedef __attribute__((ext_vector_type(16))) float          f32x16;
typedef __attribute__((ext_vector_type(8)))  unsigned short ushort8;
typedef __attribute__((ext_vector_type(4)))  unsigned int   uint4v;

#define B_    4
#define C_    64
#define N_    4096
#define LOG2E 1.4426950408889634f

// ---------------- helpers ----------------
__device__ __forceinline__ unsigned short f2bf(float f) {
    unsigned u = __builtin_bit_cast(unsigned, f);
    return (unsigned short)((u + 0x7FFFu + ((u >> 16) & 1u)) >> 16);
}
__device__ __forceinline__ float bf2f(unsigned short h) {
    return __builtin_bit_cast(float, (unsigned)h << 16);
}
__device__ __forceinline__ float fexp2(float x) {          // 2^x via v_exp_f32
    float r; asm("v_exp_f32 %0, %1" : "=v"(r) : "v"(x)); return r;
}
__device__ __forceinline__ unsigned pkbf(float lo, float hi) {  // bf16 pair pack
    unsigned r; asm("v_cvt_pk_bf16_f32 %0, %1, %2" : "=v"(r) : "v"(lo), "v"(hi));
    return r;
}
__device__ __forceinline__ f32x16 mfma32(short8 a, short8 b, f32x16 c) {
    return __builtin_amdgcn_mfma_f32_32x32x16_bf16(a, b, c, 0, 0, 0);
}

// ---------------------------------------------------------------------------
// Kernel 1: QKV projection (fp32 math) -> frag-blocked bf16 tensors.
// Q,K (hi/lo): [N/32][dstep 4][lane 64][e 8]   (lane = (row&31) + 32*d_octet)
// V          : [N/16][ct 2][lane 64][e 8]      (lane = (c&31)  + 32*k_octet)
// K scaled by log2(e) so attention works in exp2 domain.
// ---------------------------------------------------------------------------
__global__ __launch_bounds__(256) void qkv_proj(
    const float* __restrict__ x,
    const float* __restrict__ W1, const float* __restrict__ b1,
    const float* __restrict__ W2, const float* __restrict__ b2,
    const float* __restrict__ W3, const float* __restrict__ b3,
    unsigned short* __restrict__ qh_g, unsigned short* __restrict__ ql_g,
    unsigned short* __restrict__ kh_g, unsigned short* __restrict__ kl_g,
    unsigned short* __restrict__ v_g)
{
    __shared__ unsigned short Vl[64][72];                   // [c][n], padded

    const int tid = threadIdx.x;
    const int tn  = tid & 63;
    const int to  = __builtin_amdgcn_readfirstlane(tid >> 6);   // wave id = dstep
    const int b   = blockIdx.y;
    const int n0  = blockIdx.x * 64;
    const int n   = n0 + tn;

    const float* xb = x + (size_t)b * C_ * N_;
    float xv[64];
    #pragma unroll
    for (int c = 0; c < 64; ++c) xv[c] = xb[c * N_ + n];    // coalesced

    ushort8 qh8[2], ql8[2], kh8[2], kl8[2];
    #pragma unroll
    for (int og = 0; og < 16; ++og) {
        const int o = to * 16 + og;                         // wave-uniform
        const float4* w1r = (const float4*)(W1 + o * 64);
        const float4* w2r = (const float4*)(W2 + o * 64);
        const float4* w3r = (const float4*)(W3 + o * 64);
        float aq = b1[o], ak = b2[o], av = b3[o];
        #pragma unroll
        for (int c4 = 0; c4 < 16; ++c4) {
            float4 w1v = w1r[c4], w2v = w2r[c4], w3v = w3r[c4];
            const float x0 = xv[4*c4+0], x1 = xv[4*c4+1], x2 = xv[4*c4+2], x3 = xv[4*c4+3];
            aq = fmaf(w1v.x, x0, aq); aq = fmaf(w1v.y, x1, aq);
            aq = fmaf(w1v.z, x2, aq); aq = fmaf(w1v.w, x3, aq);
            ak = fmaf(w2v.x, x0, ak); ak = fmaf(w2v.y, x1, ak);
            ak = fmaf(w2v.z, x2, ak); ak = fmaf(w2v.w, x3, ak);
            av = fmaf(w3v.x, x0, av); av = fmaf(w3v.y, x1, av);
            av = fmaf(w3v.z, x2, av); av = fmaf(w3v.w, x3, av);
        }
        ak *= LOG2E;                                        // exp2-domain fold
        const int s = og >> 3, e = og & 7;
        unsigned short hsh;
        hsh = f2bf(aq); qh8[s][e] = hsh; ql8[s][e] = f2bf(aq - bf2f(hsh));
        hsh = f2bf(ak); kh8[s][e] = hsh; kl8[s][e] = f2bf(ak - bf2f(hsh));
        Vl[o][tn] = f2bf(av);
    }

    // Q/K frag-blocked stores: ((n>>5)*4 + dstep)*512 + (oct*32 + (n&31))*8
    const size_t base = (size_t)b * N_ * 64;
    const int blk = ((n >> 5) * 4 + to) * 512;
    #pragma unroll
    for (int hh = 0; hh < 2; ++hh) {
        const int off = blk + (hh * 32 + (n & 31)) * 8;
        *(ushort8*)(qh_g + base + off) = qh8[hh];
        *(ushort8*)(ql_g + base + off) = ql8[hh];
        *(ushort8*)(kh_g + base + off) = kh8[hh];
        *(ushort8*)(kl_g + base + off) = kl8[hh];
    }
    __syncthreads();

    // V frag-blocked store via LDS bounce
    #pragma unroll
    for (int i = 0; i < 2; ++i) {
        const int chunk = tid + 256 * i;                    // 0..511
        const int lane = chunk & 63;
        const int ct   = (chunk >> 6) & 1;
        const int ksl  = chunk >> 7;                        // 0..3
        const int c    = ct * 32 + (lane & 31);
        const int nl   = ksl * 16 + (lane >> 5) * 8;
        ushort8 vv = *(const ushort8*)&Vl[c][nl];
        *(ushort8*)(v_g + base + (size_t)((((n0 >> 4) + ksl) * 2 + ct) * 512) + lane * 8) = vv;
    }
}

// ---------------------------------------------------------------------------
// Kernel 2: swapped-operand MFMA flash attention, no LDS in main loop.
// 8 waves = 2 q-subtiles(32q) x 4 key-slices(1024 keys). 32x32x16 bf16 MFMA.
// S^T = mfma(A=K, B=Q) 3-split; O^T = mfma(A=V^T, B=P^T); P^T built in-reg
// via cvt_pk + shfl_xor(32). End: 4-way kslice merge in LDS + residual.
// ---------------------------------------------------------------------------
__global__ __launch_bounds__(512) void flash_attn(
    const unsigned short* __restrict__ qh_g, const unsigned short* __restrict__ ql_g,
    const unsigned short* __restrict__ kh_g, const unsigned short* __restrict__ kl_g,
    const unsigned short* __restrict__ v_g,
    const float* __restrict__ x, const float* __restrict__ alpha_p,
    float* __restrict__ out)
{
    __shared__ float Part[4][64][32];       // 32 KB  (one q-subtile round)
    __shared__ float Ml[4][2][32];          // 1 KB

    const int tid  = threadIdx.x;
    const int l    = tid & 63;
    const int w    = __builtin_amdgcn_readfirstlane(tid >> 6);
    const int h    = l >> 5;                // lane half (d/k octet)
    const int qcol = l & 31;
    const int qsub = w & 1;
    const int ksl  = w >> 1;                // key slice 0..3

    const int bid = blockIdx.x;             // XCD-pair per batch
    const int b   = (bid & 7) >> 1;
    const int qt  = ((bid >> 3) << 1) | (bid & 1);
    const int q0  = qt * 64;

    const size_t base = (size_t)b * N_ * 64;
    const unsigned short* qhB = qh_g + base;
    const unsigned short* qlB = ql_g + base;
    const unsigned short* khB = kh_g + base;
    const unsigned short* klB = kl_g + base;
    const unsigned short* vB  = v_g  + base;

    // Q fragments (resident): B-operand, frag layout == blocked layout
    const int qblk = (q0 >> 5) + qsub;
    short8 qh[4], ql[4];
    #pragma unroll
    for (int ds = 0; ds < 4; ++ds) {
        qh[ds] = *(const short8*)(qhB + (qblk * 4 + ds) * 512 + l * 8);
        ql[ds] = *(const short8*)(qlB + (qblk * 4 + ds) * 512 + l * 8);
    }

    f32x16 o0, o1;
    #pragma unroll
    for (int r = 0; r < 16; ++r) { o0[r] = 0.f; o1[r] = 0.f; }
    float m = -1e30f, lsum = 0.f;

    #pragma unroll 1
    for (int tt = 0; tt < 32; ++tt) {
        const int kb = ksl * 32 + tt;       // 32-key block index

        short8 kh[4], klo[4];
        #pragma unroll
        for (int ds = 0; ds < 4; ++ds) {
            kh[ds]  = *(const short8*)(khB + (kb * 4 + ds) * 512 + l * 8);
            klo[ds] = *(const short8*)(klB + (kb * 4 + ds) * 512 + l * 8);
        }
        short8 vfr[2][2];
        #pragma unroll
        for (int sp = 0; sp < 2; ++sp)
            #pragma unroll
            for (int ct = 0; ct < 2; ++ct)
                vfr[sp][ct] = *(const short8*)(vB + (size_t)(((kb * 2 + sp) * 2 + ct) * 512) + l * 8);

        // ---- S^T = K . Q^T, 3 independent split-accumulator chains ----
        f32x16 a0, a1, a2;
        #pragma unroll
        for (int r = 0; r < 16; ++r) { a0[r] = 0.f; a1[r] = 0.f; a2[r] = 0.f; }
        #pragma unroll
        for (int ds = 0; ds < 4; ++ds) a0 = mfma32(kh[ds],  qh[ds], a0);
        #pragma unroll
        for (int ds = 0; ds < 4; ++ds) a1 = mfma32(kh[ds],  ql[ds], a1);
        #pragma unroll
        for (int ds = 0; ds < 4; ++ds) a2 = mfma32(klo[ds], qh[ds], a2);
        f32x16 s = a0 + a1;
        s = s + a2;                         // S^T[k][q], k = (r&3)+8*(r>>2)+4h

        // ---- online softmax (per q-col; keys split across lane halves) ----
        float t0 = fmaxf(s[0], s[1]),   t1 = fmaxf(s[2], s[3]);
        float t2 = fmaxf(s[4], s[5]),   t3 = fmaxf(s[6], s[7]);
        float t4 = fmaxf(s[8], s[9]),   t5 = fmaxf(s[10], s[11]);
        float t6 = fmaxf(s[12], s[13]), t7 = fmaxf(s[14], s[15]);
        t0 = fmaxf(t0, t1); t2 = fmaxf(t2, t3); t4 = fmaxf(t4, t5); t6 = fmaxf(t6, t7);
        float tm = fmaxf(fmaxf(t0, t2), fmaxf(t4, t6));
        tm = fmaxf(tm, __shfl_xor(tm, 32));
        const int need = (tm > m + 8.0f);
        if (__any(need)) {                  // defer-max: rarely taken
            const float mn   = fmaxf(m, tm);
            const float corr = fexp2(m - mn);
            m = mn; lsum *= corr;
            o0 *= corr; o1 *= corr;
        }
        float p[16];
        #pragma unroll
        for (int r = 0; r < 16; ++r) p[r] = fexp2(s[r] - m);
        float ss = 0.f;
        #pragma unroll
        for (int r = 0; r < 16; ++r) ss += p[r];
        ss += __shfl_xor(ss, 32);
        lsum += ss;

        // ---- P^T B-fragments in-register (cvt_pk + half-swap) ----
        unsigned pw[4][2];
        #pragma unroll
        for (int mi = 0; mi < 4; ++mi) {
            pw[mi][0] = pkbf(p[4*mi+0], p[4*mi+1]);
            pw[mi][1] = pkbf(p[4*mi+2], p[4*mi+3]);
        }
        #pragma unroll
        for (int sp = 0; sp < 2; ++sp) {
            const unsigned send0 = h ? pw[2*sp][0] : pw[2*sp+1][0];
            const unsigned send1 = h ? pw[2*sp][1] : pw[2*sp+1][1];
            const unsigned r0 = (unsigned)__shfl_xor((int)send0, 32);
            const unsigned r1 = (unsigned)__shfl_xor((int)send1, 32);
            uint4v pi;
            pi[0] = h ? r0 : pw[2*sp][0];
            pi[1] = h ? r1 : pw[2*sp][1];
            pi[2] = h ? pw[2*sp+1][0] : r0;
            pi[3] = h ? pw[2*sp+1][1] : r1;
            const short8 pf = __builtin_bit_cast(short8, pi);
            o0 = mfma32(vfr[sp][0], pf, o0);
            o1 = mfma32(vfr[sp][1], pf, o1);
        }
    }

    // ---- merge 4 key-slice partials per q-subtile; residual epilogue ----
    const float alpha = alpha_p[0];
    #pragma unroll
    for (int rnd = 0; rnd < 2; ++rnd) {
        __syncthreads();
        if (qsub == rnd) {
            #pragma unroll
            for (int r = 0; r < 16; ++r) {
                const int crow = (r & 3) + 8 * (r >> 2) + 4 * h;
                Part[ksl][crow][qcol]      = o0[r];
                Part[ksl][32 + crow][qcol] = o1[r];
            }
            if (h == 0) { Ml[ksl][0][qcol] = m; Ml[ksl][1][qcol] = lsum; }
        }
        __syncthreads();
        const int q  = tid & 31;
        const int cg = tid >> 5;                            // 0..15
        const float m0 = Ml[0][0][q], m1 = Ml[1][0][q], m2 = Ml[2][0][q], m3 = Ml[3][0][q];
        const float M  = fmaxf(fmaxf(m0, m1), fmaxf(m2, m3));
        const float w0 = fexp2(m0 - M), w1 = fexp2(m1 - M);
        const float w2 = fexp2(m2 - M), w3 = fexp2(m3 - M);
        const float L  = w0 * Ml[0][1][q] + w1 * Ml[1][1][q]
                       + w2 * Ml[2][1][q] + w3 * Ml[3][1][q];
        const float invL = 1.0f / L;
        #pragma unroll
        for (int j = 0; j < 4; ++j) {
            const int c = cg * 4 + j;
            const float e = w0 * Part[0][c][q] + w1 * Part[1][c][q]
                          + w2 * Part[2][c][q] + w3 * Part[3][c][q];
            const size_t idx = (size_t)(b * 64 + c) * N_ + q0 + rnd * 32 + q;
            out[idx] = x[idx] + alpha * e * invL;
        }
    }
}

// ---------------------------------------------------------------------------
extern "C" void kernel_launch(void* const* d_in, const int* in_sizes, int n_in,
                              void* d_out, int out_size, void* d_ws, size_t ws_size,
                              hipStream_t stream)
{
    const float* x     = (const float*)d_in[0];
    const float* W1    = (const float*)d_in[1];
    const float* b1    = (const float*)d_in[2];
    const float* W2    = (const float*)d_in[3];
    const float* b2    = (const float*)d_in[4];
    const float* W3    = (const float*)d_in[5];
    const float* b3    = (const float*)d_in[6];
    const float* alpha = (const float*)d_in[7];
    float* out = (float*)d_out;

    const size_t TEN = (size_t)B_ * N_ * C_;                // 1M elems / tensor
    unsigned short* qh = (unsigned short*)d_ws;
    unsigned short* ql = qh + TEN;
    unsigned short* kh = ql + TEN;
    unsigned short* kl = kh + TEN;
    unsigned short* v  = kl + TEN;                          // 10 MiB total

    qkv_proj<<<dim3(N_ / 64, B_), 256, 0, stream>>>(x, W1, b1, W2, b2, W3, b3,
                                                    qh, ql, kh, kl, v);
    flash_attn<<<256, 512, 0, stream>>>(qh, ql, kh, kl, v, x, alpha, out);
}

// Round 7
// 133.387 us; speedup vs baseline: 3.8728x; 1.2027x over previous
//
#include <hip/hip_runtime.h>

typedef __attribute__((ext_vector_type(8)))  short          short8;
typedef __attribute__((ext_vector_type(16))) float          f32x16;
typedef __attribute__((ext_vector_type(8)))  unsigned short ushort8;
typedef __attribute__((ext_vector_type(4)))  unsigned int   uint4v;

#define B_    4
#define C_    64
#define N_    4096
#define LOG2E 1.4426950408889634f

// ---------------- helpers ----------------
__device__ __forceinline__ unsigned short f2bf(float f) {
    unsigned u = __builtin_bit_cast(unsigned, f);
    return (unsigned short)((u + 0x7FFFu + ((u >> 16) & 1u)) >> 16);
}
__device__ __forceinline__ float bf2f(unsigned short h) {
    return __builtin_bit_cast(float, (unsigned)h << 16);
}
__device__ __forceinline__ float fexp2(float x) {
    float r; asm("v_exp_f32 %0, %1" : "=v"(r) : "v"(x)); return r;
}
__device__ __forceinline__ unsigned pkbf(float lo, float hi) {
    unsigned r; asm("v_cvt_pk_bf16_f32 %0, %1, %2" : "=v"(r) : "v"(lo), "v"(hi));
    return r;
}
// Cross-half reductions: hardware-verified __shfl_xor(.,32) path (round 3
// passed with these). Two permlane-asm attempts produced half-inconsistent
// maxima (absmax 9215 / 3.94) -- do not reintroduce without isolated proof.
__device__ __forceinline__ float xhalf_max(float v) {
    return fmaxf(v, __shfl_xor(v, 32));
}
__device__ __forceinline__ float xhalf_sum(float v) {
    return v + __shfl_xor(v, 32);
}
__device__ __forceinline__ f32x16 mfma32(short8 a, short8 b, f32x16 c) {
    return __builtin_amdgcn_mfma_f32_32x32x16_bf16(a, b, c, 0, 0, 0);
}

// ---------------------------------------------------------------------------
// Kernel 1: QKV projection (fp32 math) -> frag-blocked bf16 tensors.
// Weights staged once in LDS (wave-uniform broadcast reads).
// Q,K (hi/lo): [N/32][dstep 4][lane 64][e 8];  V: [N/16][ct 2][lane 64][e 8].
// K pre-scaled by log2(e).
// ---------------------------------------------------------------------------
__global__ __launch_bounds__(256) void qkv_proj(
    const float* __restrict__ x,
    const float* __restrict__ W1, const float* __restrict__ b1,
    const float* __restrict__ W2, const float* __restrict__ b2,
    const float* __restrict__ W3, const float* __restrict__ b3,
    unsigned short* __restrict__ qh_g, unsigned short* __restrict__ ql_g,
    unsigned short* __restrict__ kh_g, unsigned short* __restrict__ kl_g,
    unsigned short* __restrict__ v_g)
{
    __shared__ __align__(16) float Wlds[3][64][64];         // 48 KB
    __shared__ unsigned short Vl[64][72];                   // 9 KB

    const int tid = threadIdx.x;
    const int tn  = tid & 63;
    const int to  = __builtin_amdgcn_readfirstlane(tid >> 6);
    const int b   = blockIdx.y;
    const int n0  = blockIdx.x * 64;
    const int n   = n0 + tn;

    {   // stage W1..W3 into LDS (each matrix = 1024 float4)
        const float* Ws[3] = {W1, W2, W3};
        #pragma unroll
        for (int mtx = 0; mtx < 3; ++mtx)
            #pragma unroll
            for (int j = 0; j < 4; ++j) {
                const int idx = j * 256 + tid;
                ((float4*)&Wlds[mtx][0][0])[idx] = ((const float4*)Ws[mtx])[idx];
            }
    }

    const float* xb = x + (size_t)b * C_ * N_;
    float xv[64];
    #pragma unroll
    for (int c = 0; c < 64; ++c) xv[c] = xb[c * N_ + n];    // coalesced
    __syncthreads();

    ushort8 qh8[2], ql8[2], kh8[2], kl8[2];
    #pragma unroll
    for (int og = 0; og < 16; ++og) {
        const int o = to * 16 + og;                         // wave-uniform
        float aq = b1[o], ak = b2[o], av = b3[o];
        #pragma unroll
        for (int c4 = 0; c4 < 16; ++c4) {
            const float4 w1v = *(const float4*)&Wlds[0][o][c4 * 4];
            const float4 w2v = *(const float4*)&Wlds[1][o][c4 * 4];
            const float4 w3v = *(const float4*)&Wlds[2][o][c4 * 4];
            const float x0 = xv[4*c4+0], x1 = xv[4*c4+1], x2 = xv[4*c4+2], x3 = xv[4*c4+3];
            aq = fmaf(w1v.x, x0, aq); aq = fmaf(w1v.y, x1, aq);
            aq = fmaf(w1v.z, x2, aq); aq = fmaf(w1v.w, x3, aq);
            ak = fmaf(w2v.x, x0, ak); ak = fmaf(w2v.y, x1, ak);
            ak = fmaf(w2v.z, x2, ak); ak = fmaf(w2v.w, x3, ak);
            av = fmaf(w3v.x, x0, av); av = fmaf(w3v.y, x1, av);
            av = fmaf(w3v.z, x2, av); av = fmaf(w3v.w, x3, av);
        }
        ak *= LOG2E;
        const int s = og >> 3, e = og & 7;
        unsigned short hsh;
        hsh = f2bf(aq); qh8[s][e] = hsh; ql8[s][e] = f2bf(aq - bf2f(hsh));
        hsh = f2bf(ak); kh8[s][e] = hsh; kl8[s][e] = f2bf(ak - bf2f(hsh));
        Vl[o][tn] = f2bf(av);
    }

    const size_t base = (size_t)b * N_ * 64;
    const int blk = ((n >> 5) * 4 + to) * 512;
    #pragma unroll
    for (int hh = 0; hh < 2; ++hh) {
        const int off = blk + (hh * 32 + (n & 31)) * 8;
        *(ushort8*)(qh_g + base + off) = qh8[hh];
        *(ushort8*)(ql_g + base + off) = ql8[hh];
        *(ushort8*)(kh_g + base + off) = kh8[hh];
        *(ushort8*)(kl_g + base + off) = kl8[hh];
    }
    __syncthreads();

    #pragma unroll
    for (int i = 0; i < 2; ++i) {
        const int chunk = tid + 256 * i;
        const int lane = chunk & 63;
        const int ct   = (chunk >> 6) & 1;
        const int ksl  = chunk >> 7;
        const int c    = ct * 32 + (lane & 31);
        const int nl   = ksl * 16 + (lane >> 5) * 8;
        ushort8 vv = *(const ushort8*)&Vl[c][nl];
        *(ushort8*)(v_g + base + (size_t)((((n0 >> 4) + ksl) * 2 + ct) * 512) + lane * 8) = vv;
    }
}

// ---------------------------------------------------------------------------
// Kernel 2: swapped-operand MFMA flash attention, software-pipelined.
// 8 waves = 2 q-subtiles(32q) x 4 key-slices(1024 keys). 32x32x16 bf16 MFMA.
// K/Kl fragments double-buffered in registers (1-iter prefetch); V loads
// issued at iteration start. All cross-half data movement via shfl_xor
// (hardware-verified round-3 semantics). Zero LDS / barriers in main loop.
// ---------------------------------------------------------------------------
__global__ __launch_bounds__(512) __attribute__((amdgpu_waves_per_eu(2)))
void flash_attn(
    const unsigned short* __restrict__ qh_g, const unsigned short* __restrict__ ql_g,
    const unsigned short* __restrict__ kh_g, const unsigned short* __restrict__ kl_g,
    const unsigned short* __restrict__ v_g,
    const float* __restrict__ x, const float* __restrict__ alpha_p,
    float* __restrict__ out)
{
    __shared__ float Part[4][64][32];
    __shared__ float Ml[4][2][32];

    const int tid  = threadIdx.x;
    const int l    = tid & 63;
    const int w    = __builtin_amdgcn_readfirstlane(tid >> 6);
    const int h    = l >> 5;            // lane half
    const int qcol = l & 31;
    const int qsub = w & 1;
    const int ksl  = w >> 1;

    const int bid = blockIdx.x;
    const int b   = (bid & 7) >> 1;
    const int qt  = ((bid >> 3) << 1) | (bid & 1);
    const int q0  = qt * 64;

    const size_t base = (size_t)b * N_ * 64;
    const unsigned short* qhB = qh_g + base;
    const unsigned short* qlB = ql_g + base;
    const unsigned short* khG = kh_g + base;
    const unsigned short* klG = kl_g + base;
    const unsigned short* vG  = v_g  + base;

    const int qblk = (q0 >> 5) + qsub;
    short8 qh[4], ql[4];
    #pragma unroll
    for (int ds = 0; ds < 4; ++ds) {
        qh[ds] = *(const short8*)(qhB + (qblk * 4 + ds) * 512 + l * 8);
        ql[ds] = *(const short8*)(qlB + (qblk * 4 + ds) * 512 + l * 8);
    }

    f32x16 o0, o1;
    #pragma unroll
    for (int r = 0; r < 16; ++r) { o0[r] = 0.f; o1[r] = 0.f; }
    float m = -1e30f, lsum = 0.f;

    short8 khA[4], klA[4], khBuf[4], klBuf[4];

#define LOADK(kb, KH, KL)                                                      \
    {   const int _kb = (kb);                                                  \
        _Pragma("unroll")                                                      \
        for (int ds = 0; ds < 4; ++ds) {                                       \
            KH[ds] = *(const short8*)(khG + (_kb * 4 + ds) * 512 + l * 8);     \
            KL[ds] = *(const short8*)(klG + (_kb * 4 + ds) * 512 + l * 8);     \
        }                                                                      \
    }

#define COMPUTE(kb, KH, KL)                                                    \
    {   const int _kb = (kb);                                                  \
        short8 vfr[2][2];                                                      \
        _Pragma("unroll")                                                      \
        for (int sp = 0; sp < 2; ++sp)                                         \
            _Pragma("unroll")                                                  \
            for (int ct = 0; ct < 2; ++ct)                                     \
                vfr[sp][ct] = *(const short8*)(vG +                            \
                    (size_t)(((_kb * 2 + sp) * 2 + ct) * 512) + l * 8);        \
        f32x16 a0, a1;                                                         \
        _Pragma("unroll")                                                      \
        for (int r = 0; r < 16; ++r) { a0[r] = 0.f; a1[r] = 0.f; }             \
        _Pragma("unroll")                                                      \
        for (int ds = 0; ds < 4; ++ds) a0 = mfma32(KH[ds], qh[ds], a0);        \
        _Pragma("unroll")                                                      \
        for (int ds = 0; ds < 4; ++ds) a0 = mfma32(KL[ds], qh[ds], a0);        \
        _Pragma("unroll")                                                      \
        for (int ds = 0; ds < 4; ++ds) a1 = mfma32(KH[ds], ql[ds], a1);        \
        f32x16 s = a0 + a1;                                                    \
        float t0 = fmaxf(s[0], s[1]),   t1 = fmaxf(s[2], s[3]);                \
        float t2 = fmaxf(s[4], s[5]),   t3 = fmaxf(s[6], s[7]);                \
        float t4 = fmaxf(s[8], s[9]),   t5 = fmaxf(s[10], s[11]);              \
        float t6 = fmaxf(s[12], s[13]), t7 = fmaxf(s[14], s[15]);              \
        t0 = fmaxf(t0, t1); t2 = fmaxf(t2, t3);                                \
        t4 = fmaxf(t4, t5); t6 = fmaxf(t6, t7);                                \
        float tm = fmaxf(fmaxf(t0, t2), fmaxf(t4, t6));                        \
        tm = xhalf_max(tm);                                                    \
        const int need = (tm > m + 8.0f);                                      \
        if (__any(need)) {                                                     \
            const float mn   = fmaxf(m, tm);                                   \
            const float corr = fexp2(m - mn);                                  \
            m = mn; lsum *= corr;                                              \
            o0 *= corr; o1 *= corr;                                            \
        }                                                                      \
        float p[16];                                                           \
        _Pragma("unroll")                                                      \
        for (int r = 0; r < 16; ++r) p[r] = fexp2(s[r] - m);                   \
        float ss = 0.f;                                                        \
        _Pragma("unroll")                                                      \
        for (int r = 0; r < 16; ++r) ss += p[r];                               \
        lsum += xhalf_sum(ss);                                                 \
        unsigned pw[4][2];                                                     \
        _Pragma("unroll")                                                      \
        for (int mi = 0; mi < 4; ++mi) {                                       \
            pw[mi][0] = pkbf(p[4*mi+0], p[4*mi+1]);                            \
            pw[mi][1] = pkbf(p[4*mi+2], p[4*mi+3]);                            \
        }                                                                      \
        _Pragma("unroll")                                                      \
        for (int sp = 0; sp < 2; ++sp) {                                       \
            const unsigned send0 = h ? pw[2*sp][0] : pw[2*sp+1][0];            \
            const unsigned send1 = h ? pw[2*sp][1] : pw[2*sp+1][1];            \
            const unsigned r0 = (unsigned)__shfl_xor((int)send0, 32);          \
            const unsigned r1 = (unsigned)__shfl_xor((int)send1, 32);          \
            uint4v pi;                                                         \
            pi[0] = h ? r0 : pw[2*sp][0];                                      \
            pi[1] = h ? r1 : pw[2*sp][1];                                      \
            pi[2] = h ? pw[2*sp+1][0] : r0;                                    \
            pi[3] = h ? pw[2*sp+1][1] : r1;                                    \
            const short8 pf = __builtin_bit_cast(short8, pi);                  \
            o0 = mfma32(vfr[sp][0], pf, o0);                                   \
            o1 = mfma32(vfr[sp][1], pf, o1);                                   \
        }                                                                      \
    }

    LOADK(ksl * 32, khA, klA);
    #pragma unroll 1
    for (int tt = 0; tt < 32; tt += 2) {
        LOADK(ksl * 32 + tt + 1, khBuf, klBuf);
        COMPUTE(ksl * 32 + tt, khA, klA);
        if (tt + 2 < 32) LOADK(ksl * 32 + tt + 2, khA, klA);
        COMPUTE(ksl * 32 + tt + 1, khBuf, klBuf);
    }
#undef LOADK
#undef COMPUTE

    // ---- merge 4 key-slice partials per q-subtile; residual epilogue ----
    const float alpha = alpha_p[0];
    #pragma unroll
    for (int rnd = 0; rnd < 2; ++rnd) {
        __syncthreads();
        if (qsub == rnd) {
            #pragma unroll
            for (int r = 0; r < 16; ++r) {
                const int crow = (r & 3) + 8 * (r >> 2) + 4 * h;
                Part[ksl][crow][qcol]      = o0[r];
                Part[ksl][32 + crow][qcol] = o1[r];
            }
            if (h == 0) { Ml[ksl][0][qcol] = m; Ml[ksl][1][qcol] = lsum; }
        }
        __syncthreads();
        const int q  = tid & 31;
        const int cg = tid >> 5;
        const float m0 = Ml[0][0][q], m1 = Ml[1][0][q], m2 = Ml[2][0][q], m3 = Ml[3][0][q];
        const float M  = fmaxf(fmaxf(m0, m1), fmaxf(m2, m3));
        const float w0 = fexp2(m0 - M), w1 = fexp2(m1 - M);
        const float w2 = fexp2(m2 - M), w3 = fexp2(m3 - M);
        const float L  = w0 * Ml[0][1][q] + w1 * Ml[1][1][q]
                       + w2 * Ml[2][1][q] + w3 * Ml[3][1][q];
        const float invL = 1.0f / L;
        #pragma unroll
        for (int j = 0; j < 4; ++j) {
            const int c = cg * 4 + j;
            const float e = w0 * Part[0][c][q] + w1 * Part[1][c][q]
                          + w2 * Part[2][c][q] + w3 * Part[3][c][q];
            const size_t idx = (size_t)(b * 64 + c) * N_ + q0 + rnd * 32 + q;
            out[idx] = x[idx] + alpha * e * invL;
        }
    }
}

// ---------------------------------------------------------------------------
extern "C" void kernel_launch(void* const* d_in, const int* in_sizes, int n_in,
                              void* d_out, int out_size, void* d_ws, size_t ws_size,
                              hipStream_t stream)
{
    const float* x     = (const float*)d_in[0];
    const float* W1    = (const float*)d_in[1];
    const float* b1    = (const float*)d_in[2];
    const float* W2    = (const float*)d_in[3];
    const float* b2    = (const float*)d_in[4];
    const float* W3    = (const float*)d_in[5];
    const float* b3    = (const float*)d_in[6];
    const float* alpha = (const float*)d_in[7];
    float* out = (float*)d_out;

    const size_t TEN = (size_t)B_ * N_ * C_;
    unsigned short* qh = (unsigned short*)d_ws;
    unsigned short* ql = qh + TEN;
    unsigned short* kh = ql + TEN;
    unsigned short* kl = kh + TEN;
    unsigned short* v  = kl + TEN;

    qkv_proj<<<dim3(N_ / 64, B_), 256, 0, stream>>>(x, W1, b1, W2, b2, W3, b3,
                                                    qh, ql, kh, kl, v);
    flash_attn<<<256, 512, 0, stream>>>(qh, ql, kh, kl, v, x, alpha, out);
}